// Round 7
// baseline (442.643 us; speedup 1.0000x reference)
//
#include <hip/hip_runtime.h>

// LSTM round 7: 2 waves/block, 8 batches/block, 1024 blocks = 2048 waves = 2/SIMD.
// B=8192, T=512, IN=5, H=32. Transposed gates (gates_T[128][cols=8 batches dup2]).
// Both waves: same 24 MFMAs (redundant on matrix pipe only). Cells split by wave:
// wave w owns acc regs {2w,2w+1} -> 2 cells/lane, 20 transc/lane (per-SIMD transc
// = R5, zero redundancy). h and x staged in tiny double-buffered LDS; ONE raw
// s_barrier per step (lgkmcnt-only drain; x global prefetch spans the barrier).
// bx/bh each = one ds_read_b128. x hi/lo split by 20 loader lanes per wave.

typedef __attribute__((ext_vector_type(8))) short short8;
typedef __attribute__((ext_vector_type(4))) float f32x4;

static constexpr int BB  = 8192;
static constexpr int TT  = 512;
static constexpr int NIN = 5;
static constexpr int HH  = 32;

__device__ __forceinline__ unsigned short bf_rne(float f) {
    unsigned int u = __float_as_uint(f);
    u = (u + 0x7FFFu + ((u >> 16) & 1u)) >> 16;
    return (unsigned short)u;
}
__device__ __forceinline__ float bf_f32(unsigned short h) {
    return __uint_as_float((unsigned int)h << 16);
}
__device__ __forceinline__ float fast_sigmoid(float x) {
    float e = __builtin_amdgcn_exp2f(-1.4426950408889634f * x);
    return __builtin_amdgcn_rcpf(1.0f + e);
}
__device__ __forceinline__ float fast_tanh(float x) {
    float e = __builtin_amdgcn_exp2f(2.8853900817779268f * x);
    return 1.0f - 2.0f * __builtin_amdgcn_rcpf(1.0f + e);
}
__device__ __forceinline__ unsigned int cvt_pk_bf16(float a, float b) {
    unsigned int r;
    asm("v_cvt_pk_bf16_f32 %0, %1, %2" : "=v"(r) : "v"(a), "v"(b));
    return r;
}

__global__ __launch_bounds__(128, 2) void lstm_dual(
    const float* __restrict__ x,     // [B, T, 5]
    const float* __restrict__ W_ih,  // [128, 5]
    const float* __restrict__ W_hh,  // [128, 32]
    const float* __restrict__ b_ih,  // [128]
    const float* __restrict__ b_hh,  // [128]
    const float* __restrict__ W_fc,  // [1, 32]
    const float* __restrict__ b_fc,  // [1]
    float* __restrict__ out)         // [B]
{
    const int tid  = threadIdx.x;
    const int w    = tid >> 6;       // wave 0/1
    const int lane = tid & 63;
    const int col  = lane & 15;
    const int kg   = lane >> 4;
    const int b    = col & 7;        // batch within group (cols dup 2x)
    const int ch   = col >> 3;       // j-half select
    const int b0   = blockIdx.x * 8;
    const int j0   = 16 * ch + 4 * kg + 2 * w;   // first of this lane's 2 cells

    // LDS: h double-buffer [2][8 batch][32 j] bf16; x stage [2][8 batch][16 slot] bf16
    // x slots: [0..4]=x_hi, [5]=1.0, [6..7]=0, [8..12]=x_lo, [13]=1.0, [14..15]=0
    __shared__ __align__(16) unsigned char hbuf[2][512];
    __shared__ __align__(16) unsigned char xbuf[2][256];
    __shared__ float parts[2][8];

    // ---- init LDS: h zeros; x constant slots ----
    if (tid < 128) {
        ((unsigned int*)hbuf)[tid] = 0u;
        ((unsigned int*)hbuf)[tid + 128] = 0u;
    }
    if (tid < 32) {          // 1.0 at slots 5 and 13 (byte 10 / 26)
        int ph = tid >> 4, bb = (tid >> 1) & 7, s = tid & 1;
        *(unsigned short*)&xbuf[ph][bb * 32 + 10 + 16 * s] = 0x3F80;
    } else if (tid < 64) {   // zeros at slots 6,7 and 14,15 (bytes 12..15 / 28..31)
        int q = tid - 32;
        int ph = q >> 4, bb = (q >> 1) & 7, s = q & 1;
        *(unsigned int*)&xbuf[ph][bb * 32 + 12 + 16 * s] = 0u;
    }

    // ---- A-fragments (loop-invariant; identical in both waves) ----
    // Tile t4: gate rows gr = 16*t4 + col, k-slice kg*8+e.
    // K-tile1 (x): kg0={Wih_hi,bias_hi}, kg1={Wih_hi,bias_lo}, kg2={Wih_lo}, kg3=0.
    short8 Ahh_hi[8], Ahh_lo[8], Ax[8];
#pragma unroll
    for (int t4 = 0; t4 < 8; ++t4) {
        const int gr = 16 * t4 + col;
#pragma unroll
        for (int e = 0; e < 8; ++e) {
            float wv = W_hh[gr * HH + kg * 8 + e];
            unsigned short hi = bf_rne(wv);
            Ahh_hi[t4][e] = (short)hi;
            Ahh_lo[t4][e] = (short)bf_rne(wv - bf_f32(hi));
        }
        float bias = b_ih[gr] + b_hh[gr];
        unsigned short bh_ = bf_rne(bias);
        unsigned short bl_ = bf_rne(bias - bf_f32(bh_));
        short8 v;
#pragma unroll
        for (int e = 0; e < 8; ++e) v[e] = 0;
        if (kg == 0 || kg == 1) {
#pragma unroll
            for (int e = 0; e < NIN; ++e) v[e] = (short)bf_rne(W_ih[gr * NIN + e]);
            v[5] = (short)((kg == 0) ? bh_ : bl_);
        } else if (kg == 2) {
#pragma unroll
            for (int e = 0; e < NIN; ++e) {
                float wv = W_ih[gr * NIN + e];
                unsigned short h2 = bf_rne(wv);
                v[e] = (short)bf_rne(wv - bf_f32(h2));
            }
        }
        Ax[t4] = v;
    }

    // ---- x loader: 20 lanes/wave own (batch = 4w + lane/5, elem = lane%5) ----
    const bool isLd = (lane < 20);
    const int lb = 4 * w + lane / 5;   // 0..7 across the two waves
    const int le = lane - 5 * (lane / 5);
    const float* px = x + ((size_t)(b0 + (lb & 7)) * TT) * NIN + le;

    auto write_x = [&](int buf, float v) {
        unsigned int t0 = cvt_pk_bf16(v, v);           // lo16 = bf16_hi(v)
        float hif = __uint_as_float(t0 << 16);
        unsigned int t1 = cvt_pk_bf16(v - hif, v - hif);
        *(unsigned short*)&xbuf[buf][lb * 32 + le * 2]      = (unsigned short)t0;
        *(unsigned short*)&xbuf[buf][lb * 32 + 16 + le * 2] = (unsigned short)t1;
    };

    float xv = 0.f;
    if (isLd) {
        write_x(0, px[0]);       // x(t=0) -> xbuf[0]
        xv = px[NIN];            // x(t=1) in flight
    }
    __syncthreads();

    float cA = 0.f, cB = 0.f, hA = 0.f, hB = 0.f;
    const f32x4 z = {0.f, 0.f, 0.f, 0.f};

    const unsigned bh_off = (unsigned)(b * 64 + kg * 16);
    const unsigned bx_off = (unsigned)(b * 32 + ((kg == 1) ? 16 : 0));
    const unsigned hw_off = (unsigned)(b * 64 + j0 * 2);

    auto step = [&](int t, int cur) {
        const int nxt = cur ^ 1;

        // B-frags: one b128 each (data guaranteed by previous barrier)
        short8 bh = *(const short8*)&hbuf[cur][bh_off];
        short8 bx = *(const short8*)&xbuf[cur][bx_off];

        // 24 MFMAs: 8 independent 3-chains
        f32x4 acc[8];
#pragma unroll
        for (int t4 = 0; t4 < 8; ++t4)
            acc[t4] = __builtin_amdgcn_mfma_f32_16x16x32_bf16(Ahh_lo[t4], bh, z, 0, 0, 0);
#pragma unroll
        for (int t4 = 0; t4 < 8; ++t4)
            acc[t4] = __builtin_amdgcn_mfma_f32_16x16x32_bf16(Ahh_hi[t4], bh, acc[t4], 0, 0, 0);
#pragma unroll
        for (int t4 = 0; t4 < 8; ++t4)
            acc[t4] = __builtin_amdgcn_mfma_f32_16x16x32_bf16(Ax[t4], bx, acc[t4], 0, 0, 0);

        // cells: wave w consumes acc regs {2w, 2w+1}; tile pair by ch (cndmask)
        float giA, gfA, ggA, goA, giB, gfB, ggB, goB;
        if (w == 0) {
            giA = ch ? acc[1][0] : acc[0][0];  giB = ch ? acc[1][1] : acc[0][1];
            gfA = ch ? acc[3][0] : acc[2][0];  gfB = ch ? acc[3][1] : acc[2][1];
            ggA = ch ? acc[5][0] : acc[4][0];  ggB = ch ? acc[5][1] : acc[4][1];
            goA = ch ? acc[7][0] : acc[6][0];  goB = ch ? acc[7][1] : acc[6][1];
        } else {
            giA = ch ? acc[1][2] : acc[0][2];  giB = ch ? acc[1][3] : acc[0][3];
            gfA = ch ? acc[3][2] : acc[2][2];  gfB = ch ? acc[3][3] : acc[2][3];
            ggA = ch ? acc[5][2] : acc[4][2];  ggB = ch ? acc[5][3] : acc[4][3];
            goA = ch ? acc[7][2] : acc[6][2];  goB = ch ? acc[7][3] : acc[6][3];
        }
        {
            float iv = fast_sigmoid(giA);
            float fv = fast_sigmoid(gfA);
            float gv = fast_tanh(ggA);
            float ov = fast_sigmoid(goA);
            cA = fv * cA + iv * gv;
            hA = ov * fast_tanh(cA);
        }
        {
            float iv = fast_sigmoid(giB);
            float fv = fast_sigmoid(gfB);
            float gv = fast_tanh(ggB);
            float ov = fast_sigmoid(goB);
            cB = fv * cB + iv * gv;
            hB = ov * fast_tanh(cB);
        }

        // h -> LDS (j0 even; lo16 = h[j0], hi16 = h[j0+1])
        *(unsigned int*)&hbuf[nxt][hw_off] = cvt_pk_bf16(hA, hB);

        // x stage for t+1; prefetch t+2 (global load spans the barrier)
        if (isLd) {
            write_x(nxt, xv);
            const int tn = (t + 2 < TT) ? (t + 2) : (TT - 1);
            xv = px[(size_t)tn * NIN];
        }

        asm volatile("s_waitcnt lgkmcnt(0)" ::: "memory");
        __builtin_amdgcn_s_barrier();
    };

#pragma unroll 1
    for (int t = 0; t < TT; t += 2) {
        step(t, 0);
        step(t + 1, 1);
    }

    // ---- head: out[b] = sum_j h[b][j]*W_fc[j] + b_fc ----
    float v = hA * W_fc[j0] + hB * W_fc[j0 + 1];
    v += __shfl_xor(v, 8);    // combine ch halves
    v += __shfl_xor(v, 16);   // combine kg
    v += __shfl_xor(v, 32);
    if (lane < 8) parts[w][lane] = v;
    __syncthreads();
    if (tid < 8) out[b0 + tid] = parts[0][tid] + parts[1][tid] + b_fc[0];
}

extern "C" void kernel_launch(void* const* d_in, const int* in_sizes, int n_in,
                              void* d_out, int out_size, void* d_ws, size_t ws_size,
                              hipStream_t stream) {
    const float* x    = (const float*)d_in[0];
    const float* W_ih = (const float*)d_in[1];
    const float* W_hh = (const float*)d_in[2];
    const float* b_ih = (const float*)d_in[3];
    const float* b_hh = (const float*)d_in[4];
    const float* W_fc = (const float*)d_in[5];
    const float* b_fc = (const float*)d_in[6];
    float* out = (float*)d_out;

    lstm_dual<<<dim3(BB / 8), dim3(128), 0, stream>>>(
        x, W_ih, W_hh, b_ih, b_hh, W_fc, b_fc, out);
}